// Round 3
// baseline (139.775 us; speedup 1.0000x reference)
//
#include <hip/hip_runtime.h>

// CensusLoss = mean |census(pred)-census(target)|, census = 48 bits of
// (center > neighbor) on grayscale, 7x7 reflect-padded window.
// = (# of disagreeing predicates) / (8*48*512*512).
//
// Two passes:
//  1) gray: float4-coalesced 3ch->gray for both images into d_ws (L3-resident).
//  2) census: 32x32 tiles, column-major LDS halo (PITCH 44: 16B-aligned
//     columns => ds_read_b128; bank-group stride 11 (odd mod 8) => uniform
//     bank coverage for b128), ballot+popcount so the mismatch count is
//     accumulated on the scalar pipe, wave-uniform.

#define BATCH 8
#define HH 512
#define WW 512
#define PLANE (HH * WW)          // 262144
#define PLANE4 (PLANE / 4)       // 65536 float4s per image-plane

// ---------------- pass 1: grayscale ----------------
#define NV (BATCH * PLANE4)      // float4s per image = 524288

__global__ __launch_bounds__(256)
void gray_kernel(const float* __restrict__ pred,
                 const float* __restrict__ target,
                 float* __restrict__ gp, float* __restrict__ gt) {
    int gid = blockIdx.x * 256 + threadIdx.x;   // 0 .. 2*NV-1
    const float4* src;
    float4* dst;
    if (gid < NV) {
        src = (const float4*)pred;  dst = (float4*)gp;
    } else {
        src = (const float4*)target; dst = (float4*)gt; gid -= NV;
    }
    const int b  = gid >> 16;          // / PLANE4
    const int p4 = gid & (PLANE4 - 1);
    const int base = b * 3 * PLANE4 + p4;
    const float4 r  = src[base];
    const float4 g  = src[base + PLANE4];
    const float4 bl = src[base + 2 * PLANE4];
    float4 o;
    o.x = 0.299f * r.x + 0.587f * g.x + 0.114f * bl.x;
    o.y = 0.299f * r.y + 0.587f * g.y + 0.114f * bl.y;
    o.z = 0.299f * r.z + 0.587f * g.z + 0.114f * bl.z;
    o.w = 0.299f * r.w + 0.587f * g.w + 0.114f * bl.w;
    dst[gid] = o;   // gid == b*PLANE4 + p4; dst is [B][H][W]
}

// ---------------- pass 2: census + count ----------------
#define TILE 32
#define RPT 4                    // pixel rows per thread (8 thread-rows)
#define LT 38                    // TILE + 6 halo
#define PITCH 44                 // %4==0 -> 16B-aligned columns; PITCH/4=11 odd -> good b128 banking

__global__ __launch_bounds__(256)
void census_kernel(const float* __restrict__ gp,
                   const float* __restrict__ gt,
                   float* __restrict__ out) {
    __shared__ float sP[LT][PITCH];   // column-major: sP[x][y]
    __shared__ float sT[LT][PITCH];

    const int b   = blockIdx.z;
    const int ty0 = blockIdx.y * TILE;
    const int tx0 = blockIdx.x * TILE;
    const float* __restrict__ Pb = gp + (size_t)b * PLANE;
    const float* __restrict__ Tb = gt + (size_t)b * PLANE;

    // Stage 38x38 gray halo, reflect indexing. Consecutive lanes -> consecutive
    // gx (coalesced global read).
    for (int idx = threadIdx.x; idx < LT * LT; idx += 256) {
        const int ly = idx / LT;        // image row
        const int lx = idx - ly * LT;   // image col
        int gy = ty0 + ly - 3;
        int gx = tx0 + lx - 3;
        gy = gy < 0 ? -gy : (gy >= HH ? 2 * HH - 2 - gy : gy);
        gx = gx < 0 ? -gx : (gx >= WW ? 2 * WW - 2 - gx : gx);
        const int off = gy * WW + gx;
        sP[lx][ly] = Pb[off];
        sT[lx][ly] = Tb[off];
    }
    __syncthreads();

    const int c   = threadIdx.x & 31;          // tile column
    const int pr0 = (threadIdx.x >> 5) * RPT;  // first pixel row (0,4,..,28)

    // Centers: pixel (pr0+p, c) -> sX[c+3][pr0+3+p]
    float cP[RPT], cT[RPT];
    #pragma unroll
    for (int p = 0; p < RPT; ++p) {
        cP[p] = sP[c + 3][pr0 + 3 + p];
        cT[p] = sT[c + 3][pr0 + 3 + p];
    }

    // Wave-uniform mismatch count via ballot: compare is VALU (v_cmp -> sgpr
    // pair), xor+popcount ride the scalar pipe. Each ballot covers 64 distinct
    // pixels (2 thread-rows x 32 cols), so lane 0's running sum is the wave
    // total — no shuffle reduction needed.
    long long scnt = 0;
    #pragma unroll
    for (int j = 0; j < 7; ++j) {
        const float* __restrict__ colP = &sP[c + j][pr0];  // 16B-aligned (pr0%4==0, PITCH%4==0)
        const float* __restrict__ colT = &sT[c + j][pr0];
        float wP[RPT + 6], wT[RPT + 6];
        #pragma unroll
        for (int i = 0; i < RPT + 6; ++i) { wP[i] = colP[i]; wT[i] = colT[i]; }
        #pragma unroll
        for (int p = 0; p < RPT; ++p) {
            #pragma unroll
            for (int i = 0; i < 7; ++i) {
                if (j == 3 && i == 3) continue;   // center
                const unsigned long long bp = __ballot(cP[p] > wP[p + i]);
                const unsigned long long bt = __ballot(cT[p] > wT[p + i]);
                scnt += __popcll(bp ^ bt);
            }
        }
    }

    __shared__ int wsum[4];
    if ((threadIdx.x & 63) == 0) wsum[threadIdx.x >> 6] = (int)scnt;
    __syncthreads();
    if (threadIdx.x == 0) {
        const int total = wsum[0] + wsum[1] + wsum[2] + wsum[3];
        // N = 8 * 48 * 512 * 512 = 100663296
        atomicAdd(out, (float)total * (1.0f / 100663296.0f));
    }
}

extern "C" void kernel_launch(void* const* d_in, const int* in_sizes, int n_in,
                              void* d_out, int out_size, void* d_ws, size_t ws_size,
                              hipStream_t stream) {
    const float* pred   = (const float*)d_in[0];
    const float* target = (const float*)d_in[1];
    float* out = (float*)d_out;
    float* gp = (float*)d_ws;                       // 8*512*512 floats (8 MB)
    float* gt = gp + (size_t)BATCH * PLANE;

    hipMemsetAsync(out, 0, sizeof(float), stream);  // d_out is poisoned 0xAA

    gray_kernel<<<dim3(2 * NV / 256), 256, 0, stream>>>(pred, target, gp, gt);

    dim3 g2(WW / TILE, HH / TILE, BATCH);           // (16,16,8) = 2048 blocks
    census_kernel<<<g2, 256, 0, stream>>>(gp, gt, out);
}

// Round 4
// 101.305 us; speedup vs baseline: 1.3798x; 1.3798x over previous
//
#include <hip/hip_runtime.h>

// CensusLoss = mean |census(pred)-census(target)| = mismatch_count / (8*48*512*512).
// Single fused kernel: gray-on-the-fly into column-major LDS halo tile,
// float4-vectorized LDS column reads, per-lane predicated mismatch count,
// block reduce, one atomicAdd.
//
// Tile 64 wide x 32 tall, 512 threads, each thread owns 4 pixel rows of one
// column. Halo = 70 cols x 38 rows. LDS column-major [x][y], PITCH 44:
//  - columns are 176 B (16B-aligned) -> ds_read_b128 for the 10-row window
//  - read banking: lane stride 44 dwords -> 4-dword groups tile all 32 banks
//  - staging writes are 8-way conflicted (stride 12 mod 32) -> ~624 cyc/block,
//    budgeted (~2 us chip-wide, overlapped with HBM-bound staging)
// Occupancy: LDS 24.6 KB, launch_bounds(512,8) -> 4 blocks/CU = 32 waves/CU.

#define BATCH 8
#define HH 512
#define WW 512
#define PLANE (HH * WW)
#define TW 64
#define TH 32
#define LW 70            // TW + 6
#define LH 38            // TH + 6
#define PITCH 44         // y-pitch: 16B-aligned columns, good b128 banking
#define NTHREADS 512

__global__ __launch_bounds__(NTHREADS, 8)
void census_fused(const float* __restrict__ pred,
                  const float* __restrict__ target,
                  float* __restrict__ out) {
    __shared__ __align__(16) float sP[LW][PITCH];   // column-major: [x][y]
    __shared__ __align__(16) float sT[LW][PITCH];

    const int b   = blockIdx.z;
    const int ty0 = blockIdx.y * TH;
    const int tx0 = blockIdx.x * TW;
    const float* __restrict__ pb = pred + (size_t)b * 3 * PLANE;
    const float* __restrict__ tb = target + (size_t)b * 3 * PLANE;

    // Stage 70x38 gray halo. Consecutive lanes -> consecutive gx (coalesced
    // global loads, 6 independent loads per pixel for vmcnt overlap).
    for (int idx = threadIdx.x; idx < LW * LH; idx += NTHREADS) {
        const int ly = idx / LW;        // halo row
        const int lx = idx - ly * LW;   // halo col
        int gy = ty0 + ly - 3;
        int gx = tx0 + lx - 3;
        gy = gy < 0 ? -gy : (gy >= HH ? 2 * HH - 2 - gy : gy);
        gx = gx < 0 ? -gx : (gx >= WW ? 2 * WW - 2 - gx : gx);
        const int off = gy * WW + gx;
        const float p0 = pb[off], p1 = pb[off + PLANE], p2 = pb[off + 2 * PLANE];
        const float t0 = tb[off], t1 = tb[off + PLANE], t2 = tb[off + 2 * PLANE];
        sP[lx][ly] = 0.299f * p0 + 0.587f * p1 + 0.114f * p2;
        sT[lx][ly] = 0.299f * t0 + 0.587f * t1 + 0.114f * t2;
    }
    __syncthreads();

    const int c   = threadIdx.x & 63;          // tile column (one wave = one row band)
    const int pr0 = (threadIdx.x >> 6) * 4;    // first pixel row: 0,4,...,28

    // Center pixel (tx0+c, ty0+pr0+p) <-> halo [c+3][pr0+3+p].
    // Window per column: halo rows pr0..pr0+9 (covers dy in [-3,3] for 4 px).
    int cnt = 0;
    float cP[4], cT[4];

    // dx = 0 column first (captures centers from its own window).
    {
        const float* colP = &sP[c + 3][pr0];   // 16B-aligned: (c+3)*44 and pr0 are mult of 4
        const float* colT = &sT[c + 3][pr0];
        float wP[10], wT[10];
        *(float4*)&wP[0] = *(const float4*)(colP);
        *(float4*)&wP[4] = *(const float4*)(colP + 4);
        *(float2*)&wP[8] = *(const float2*)(colP + 8);
        *(float4*)&wT[0] = *(const float4*)(colT);
        *(float4*)&wT[4] = *(const float4*)(colT + 4);
        *(float2*)&wT[8] = *(const float2*)(colT + 8);
        #pragma unroll
        for (int p = 0; p < 4; ++p) { cP[p] = wP[3 + p]; cT[p] = wT[3 + p]; }
        #pragma unroll
        for (int p = 0; p < 4; ++p) {
            #pragma unroll
            for (int dy = -3; dy <= 3; ++dy) {
                if (dy == 0) continue;          // center itself
                const bool bp = cP[p] > wP[3 + p + dy];
                const bool bt = cT[p] > wT[3 + p + dy];
                cnt += (bp != bt) ? 1 : 0;
            }
        }
    }
    // Remaining 6 columns (dx = -3..3, dx != 0), full dy in [-3,3].
    #pragma unroll
    for (int t = 0; t < 6; ++t) {
        const int jj = (t < 3) ? t : t + 1;     // 0,1,2,4,5,6
        const float* colP = &sP[c + jj][pr0];
        const float* colT = &sT[c + jj][pr0];
        float wP[10], wT[10];
        *(float4*)&wP[0] = *(const float4*)(colP);
        *(float4*)&wP[4] = *(const float4*)(colP + 4);
        *(float2*)&wP[8] = *(const float2*)(colP + 8);
        *(float4*)&wT[0] = *(const float4*)(colT);
        *(float4*)&wT[4] = *(const float4*)(colT + 4);
        *(float2*)&wT[8] = *(const float2*)(colT + 8);
        #pragma unroll
        for (int p = 0; p < 4; ++p) {
            #pragma unroll
            for (int dy = -3; dy <= 3; ++dy) {
                const bool bp = cP[p] > wP[3 + p + dy];
                const bool bt = cT[p] > wT[3 + p + dy];
                cnt += (bp != bt) ? 1 : 0;
            }
        }
    }

    // Reduce: 64-lane shuffle, then cross-wave LDS, one atomic per block.
    #pragma unroll
    for (int o = 32; o > 0; o >>= 1) cnt += __shfl_down(cnt, o, 64);
    __shared__ int wsum[8];
    if ((threadIdx.x & 63) == 0) wsum[threadIdx.x >> 6] = cnt;
    __syncthreads();
    if (threadIdx.x == 0) {
        int tot = 0;
        #pragma unroll
        for (int w = 0; w < 8; ++w) tot += wsum[w];
        // N = 8 * 48 * 512 * 512 = 100663296
        atomicAdd(out, (float)tot * (1.0f / 100663296.0f));
    }
}

extern "C" void kernel_launch(void* const* d_in, const int* in_sizes, int n_in,
                              void* d_out, int out_size, void* d_ws, size_t ws_size,
                              hipStream_t stream) {
    const float* pred   = (const float*)d_in[0];
    const float* target = (const float*)d_in[1];
    float* out = (float*)d_out;

    hipMemsetAsync(out, 0, sizeof(float), stream);   // d_out poisoned 0xAA

    dim3 grid(WW / TW, HH / TH, BATCH);              // (8, 16, 8) = 1024 blocks
    census_fused<<<grid, NTHREADS, 0, stream>>>(pred, target, out);
}